// Round 1
// baseline (323.352 us; speedup 1.0000x reference)
//
#include <hip/hip_runtime.h>
#include <hip/hip_cooperative_groups.h>
#include <math.h>

namespace cg = cooperative_groups;

// ---------------------------------------------------------------------------
// TwoSimplicialAttention, MI355X. Structure exploit: mask kills attention for
// all s < 2016; only last 32 rows/batch (64 rows) carry attention. Everything
// else is out = LayerNorm(x).
//
// R3: single cooperative kernel. 4 phases separated by grid.sync():
//   P1 proj (ksplit partials, no atomics)  || LN rows [0,1792)
//   P2 attn (sums 4 partials at staging)   || LN rows [1792,3392)
//   P3 Z@W_O (8 ksplit partials)           || LN rows [3392,4032)
//   P4 window rows: LN(x + sum of delta partials)
// Old 5-kernel path kept as fallback if cooperative launch unavailable.
// ---------------------------------------------------------------------------

#define XS 68   // attn LDS pad

// ===== fused ws layout (floats) =====
#define YP_OFF   0            // 4 partials x [64][4096]  cols = [Q|K|Kp|V]
#define YP_STR   262144
#define ZF_OFF   1048576      // [64][1024]
#define DP_OFF   1114112      // 8 partials x [64][1024]
#define DP_STR   65536
#define FUSED_WS_FLOATS 1638400   // 6.55 MB

// ===== legacy ws layout (fallback path) =====
#define YQ_OFF    0
#define YK_OFF    65536
#define YKP_OFF   131072
#define YV_OFF    196608
#define Z_OFF     262144
#define DELTA_OFF 327680
#define WS_FLOATS 393216

// ---------------------------------------------------------------------------
// LayerNorm of one row (no delta), one wave per row.
__device__ __forceinline__ void ln_row(
    const float4* __restrict__ x4, const float4* __restrict__ g4,
    const float4* __restrict__ b4, float4* __restrict__ out4,
    int row, int lane) {
  float4 v[4];
  #pragma unroll
  for (int i = 0; i < 4; i++) v[i] = x4[row * 256 + i * 64 + lane];
  float sum = 0.f, ss = 0.f;
  #pragma unroll
  for (int i = 0; i < 4; i++) {
    sum += v[i].x + v[i].y + v[i].z + v[i].w;
    ss  += v[i].x * v[i].x + v[i].y * v[i].y + v[i].z * v[i].z + v[i].w * v[i].w;
  }
  #pragma unroll
  for (int off = 1; off < 64; off <<= 1) {
    sum += __shfl_xor(sum, off);
    ss  += __shfl_xor(ss, off);
  }
  float mu   = sum * (1.f / 1024.f);
  float rstd = rsqrtf(ss * (1.f / 1024.f) - mu * mu + 1e-5f);
  #pragma unroll
  for (int i = 0; i < 4; i++) {
    float4 g  = g4[i * 64 + lane];
    float4 be = b4[i * 64 + lane];
    float4 o;
    o.x = (v[i].x - mu) * rstd * g.x + be.x;
    o.y = (v[i].y - mu) * rstd * g.y + be.y;
    o.z = (v[i].z - mu) * rstd * g.z + be.z;
    o.w = (v[i].w - mu) * rstd * g.w + be.w;
    out4[row * 256 + i * 64 + lane] = o;
  }
}

// ---------------------------------------------------------------------------
__global__ __launch_bounds__(256, 2) void fused_kernel(
    const float* __restrict__ x,
    const float* __restrict__ Wq, const float* __restrict__ Wk,
    const float* __restrict__ Wkp, const float* __restrict__ Wv,
    const float* __restrict__ Wo,
    const float* __restrict__ gam, const float* __restrict__ bet,
    float* __restrict__ out, float* __restrict__ ws) {
  // smem union across phases: proj/wo need 64*65=4160, attn needs 11008.
  __shared__ float smem[11008];   // 44 KB -> 2 blocks/CU fits (88 < 160 KB)
  const int tid  = threadIdx.x;
  const int bid  = blockIdx.x;
  const int wave = __builtin_amdgcn_readfirstlane(tid >> 6);  // uniform
  const int lane = tid & 63;
  const float4* x4   = (const float4*)x;
  const float4* g4   = (const float4*)gam;
  const float4* b4   = (const float4*)bet;
  float4*       out4 = (float4*)out;

  // ======== P1: proj partials (256 blocks) || LN rows [0,1792) ========
  if (bid < 256) {
    float* xs = smem;                       // [64 k][65]
    const int cb = bid & 63, ks = bid >> 6; // colblock, ksplit
    const int col0 = cb * 64;               // global Y col (0..4095)
    const int z = cb >> 4;                  // which W matrix
    const int colz = col0 & 1023;
    const float* __restrict__ W =
        (z == 0) ? Wq : ((z == 1) ? Wk : ((z == 2) ? Wkp : Wv));
    float acc[16];
    #pragma unroll
    for (int c = 0; c < 16; c++) acc[c] = 0.f;

    for (int cc = 0; cc < 4; cc++) {        // 4 chunks of 64 k  (k = ks*256..)
      const int kb = ks * 256 + cc * 64;
      #pragma unroll
      for (int i = 0; i < 4; i++) {         // stage x^T: 64 rows x 64 k
        int e = i * 256 + tid;
        int r = e >> 4, q = e & 15;
        int bb = r >> 5, t = r & 31;
        float4 v = *(const float4*)(x + ((bb * 2048 + 2016 + t) * 1024 + kb + q * 4));
        xs[(q * 4 + 0) * 65 + r] = v.x;
        xs[(q * 4 + 1) * 65 + r] = v.y;
        xs[(q * 4 + 2) * 65 + r] = v.z;
        xs[(q * 4 + 3) * 65 + r] = v.w;
      }
      __syncthreads();
      const float* __restrict__ Wt = W + (size_t)kb * 1024 + colz + wave * 16;
      #pragma unroll 4
      for (int kk = 0; kk < 64; kk++) {
        float xv = xs[kk * 65 + lane];                 // lane = row
        const float* __restrict__ wrow = Wt + kk * 1024;  // uniform -> s_load
        #pragma unroll
        for (int c = 0; c < 16; c++) acc[c] = fmaf(xv, wrow[c], acc[c]);
      }
      __syncthreads();
    }
    // transpose through LDS, coalesced partial store (no atomics)
    #pragma unroll
    for (int c = 0; c < 16; c++) xs[lane * 65 + wave * 16 + c] = acc[c];
    __syncthreads();
    float* __restrict__ Yo = ws + YP_OFF + ks * YP_STR + col0;
    #pragma unroll
    for (int i = 0; i < 16; i++) {
      int r = wave * 16 + i;
      Yo[r * 4096 + lane] = xs[r * 65 + lane];
    }
  } else {
    const int gw = (bid - 256) * 4 + wave;  // 1024 LN waves
    for (int idx = gw; idx < 1792; idx += 1024)
      ln_row(x4, g4, b4, out4, idx, lane);  // idx < 2016 -> row = idx
  }
  cg::this_grid().sync();

  // ======== P2: attention (256 blocks) || LN rows [1792,3392) ========
  if (bid < 256) {
    float* Kn = smem;               // 32*XS
    float* Kp = smem + 2176;
    float* Vs = smem + 4352;
    float* Pt = smem + 6528;        // 4 waves x 32*33
    float* qs = smem + 10752;       // 4 waves x 64
    const int mb = bid & 7, h = (bid >> 3) & 15, b = bid >> 7;

    #pragma unroll
    for (int i = 0; i < 8; i++) {   // stage K/Kp/V, summing 4 ksplit partials
      int e = i * 256 + tid;
      int row = e >> 6, d = e & 63;
      int src = (b * 32 + row) * 4096 + h * 64 + d;
      float kn = 0.f, kp = 0.f, vv = 0.f;
      #pragma unroll
      for (int p = 0; p < 4; p++) {
        const float* Yp = ws + p * YP_STR + src;
        kn += Yp[1024]; kp += Yp[2048]; vv += Yp[3072];
      }
      Kn[row * XS + d] = kn; Kp[row * XS + d] = kp; Vs[row * XS + d] = vv;
    }
    __syncthreads();

    for (int rr = 0; rr < 8; rr++) {          // l2-normalize K, Kp rows
      int row = wave * 8 + rr;
      float kv = Kn[row * XS + lane];
      float s2 = kv * kv;
      #pragma unroll
      for (int off = 1; off < 64; off <<= 1) s2 += __shfl_xor(s2, off);
      Kn[row * XS + lane] = kv * (1.f / (sqrtf(s2) + 1e-7f));
      float pv = Kp[row * XS + lane];
      float p2 = pv * pv;
      #pragma unroll
      for (int off = 1; off < 64; off <<= 1) p2 += __shfl_xor(p2, off);
      Kp[row * XS + lane] = pv * (1.f / (sqrtf(p2) + 1e-7f));
    }
    __syncthreads();

    const int m = mb * 4 + wave;
    const int r = b * 32 + m;

    float q = 0.f;
    #pragma unroll
    for (int p = 0; p < 4; p++) q += ws[p * YP_STR + r * 4096 + h * 64 + lane];
    float q2 = q * q;
    #pragma unroll
    for (int off = 1; off < 64; off <<= 1) q2 += __shfl_xor(q2, off);
    q *= (1.f / (sqrtf(q2) + 1e-7f));
    float* qsw = qs + wave * 64;
    qsw[lane] = q;
    __builtin_amdgcn_wave_barrier();

    const int lj = lane >> 3, lk = lane & 7;
    float acc[4][4];
    #pragma unroll
    for (int a = 0; a < 4; a++)
      #pragma unroll
      for (int c = 0; c < 4; c++) acc[a][c] = 0.f;

    const float* qw = qsw;
    for (int dq = 0; dq < 16; dq++) {
      float4 q4 = *(const float4*)(qw + dq * 4);
      float4 t4[4], kp4[4];
      #pragma unroll
      for (int tj = 0; tj < 4; tj++) {
        float4 kv = *(const float4*)(Kn + (lj * 4 + tj) * XS + dq * 4);
        t4[tj].x = q4.x * kv.x; t4[tj].y = q4.y * kv.y;
        t4[tj].z = q4.z * kv.z; t4[tj].w = q4.w * kv.w;
      }
      #pragma unroll
      for (int tk = 0; tk < 4; tk++)
        kp4[tk] = *(const float4*)(Kp + (lk * 4 + tk) * XS + dq * 4);
      #pragma unroll
      for (int tj = 0; tj < 4; tj++)
        #pragma unroll
        for (int tk = 0; tk < 4; tk++)
          acc[tj][tk] += t4[tj].x * kp4[tk].x + t4[tj].y * kp4[tk].y
                       + t4[tj].z * kp4[tk].z + t4[tj].w * kp4[tk].w;
    }

    float amax = -1e30f;
    #pragma unroll
    for (int tj = 0; tj < 4; tj++)
      #pragma unroll
      for (int tk = 0; tk < 4; tk++) {
        int j = lj * 4 + tj, k = lk * 4 + tk;
        if (j <= m && k <= m) amax = fmaxf(amax, acc[tj][tk] * 0.125f);
      }
    #pragma unroll
    for (int off = 1; off < 64; off <<= 1) amax = fmaxf(amax, __shfl_xor(amax, off));

    float lsum = 0.f;
    float* ptw = Pt + wave * 1056;
    #pragma unroll
    for (int tj = 0; tj < 4; tj++)
      #pragma unroll
      for (int tk = 0; tk < 4; tk++) {
        int j = lj * 4 + tj, k = lk * 4 + tk;
        float e = 0.f;
        if (j <= m && k <= m) e = __expf(acc[tj][tk] * 0.125f - amax);
        lsum += e;
        ptw[k * 33 + j] = e;
      }
    #pragma unroll
    for (int off = 1; off < 64; off <<= 1) lsum += __shfl_xor(lsum, off);
    float inv = 1.f / lsum;
    __builtin_amdgcn_wave_barrier();

    float vreg[32];
    #pragma unroll
    for (int k = 0; k < 32; k++) vreg[k] = Vs[k * XS + lane];
    float zacc = 0.f;
    for (int k = 0; k <= m; k++) {
      float g = 0.f;
      #pragma unroll
      for (int j = 0; j < 32; j++) g += ptw[k * 33 + j] * vreg[j];
      zacc += g * vreg[k];
    }
    ws[ZF_OFF + r * 1024 + h * 64 + lane] = zacc * inv;
  } else {
    const int gw = (bid - 256) * 4 + wave;
    for (int idx = 1792 + gw; idx < 3392; idx += 1024) {
      int row = (idx < 2016) ? idx : idx + 32;
      ln_row(x4, g4, b4, out4, row, lane);
    }
  }
  cg::this_grid().sync();

  // ======== P3: delta partials = Z @ W_O (128 blocks) || LN [3392,4032) ====
  if (bid < 128) {
    float* xs = smem;
    const int cb = bid >> 3, ks = bid & 7;   // 16 colblocks x 8 ksplits
    const int col0 = cb * 64;
    float acc[16];
    #pragma unroll
    for (int c = 0; c < 16; c++) acc[c] = 0.f;

    for (int cc = 0; cc < 2; cc++) {         // 2 chunks of 64 k (k = ks*128..)
      const int kb = ks * 128 + cc * 64;
      #pragma unroll
      for (int i = 0; i < 4; i++) {
        int e = i * 256 + tid;
        int r = e >> 4, q = e & 15;
        float4 v = *(const float4*)(ws + ZF_OFF + r * 1024 + kb + q * 4);
        xs[(q * 4 + 0) * 65 + r] = v.x;
        xs[(q * 4 + 1) * 65 + r] = v.y;
        xs[(q * 4 + 2) * 65 + r] = v.z;
        xs[(q * 4 + 3) * 65 + r] = v.w;
      }
      __syncthreads();
      const float* __restrict__ Wt = Wo + (size_t)kb * 1024 + col0 + wave * 16;
      #pragma unroll 4
      for (int kk = 0; kk < 64; kk++) {
        float xv = xs[kk * 65 + lane];
        const float* __restrict__ wrow = Wt + kk * 1024;
        #pragma unroll
        for (int c = 0; c < 16; c++) acc[c] = fmaf(xv, wrow[c], acc[c]);
      }
      __syncthreads();
    }
    #pragma unroll
    for (int c = 0; c < 16; c++) xs[lane * 65 + wave * 16 + c] = acc[c];
    __syncthreads();
    float* __restrict__ Dp = ws + DP_OFF + ks * DP_STR + col0;
    #pragma unroll
    for (int i = 0; i < 16; i++) {
      int r = wave * 16 + i;
      Dp[r * 1024 + lane] = xs[r * 65 + lane];
    }
  } else {
    const int gw = (bid - 128) * 4 + wave;   // 1536 LN waves
    for (int idx = 3392 + gw; idx < 4032; idx += 1536) {
      int row = (idx < 2016) ? idx : idx + 32;
      ln_row(x4, g4, b4, out4, row, lane);
    }
  }
  cg::this_grid().sync();

  // ======== P4: window rows LN(x + sum of 8 delta partials) ========
  if (bid < 16) {
    const int wr  = bid * 4 + wave;                        // 0..63
    const int row = (wr >> 5) * 2048 + 2016 + (wr & 31);
    const float4* dp4 = (const float4*)(ws + DP_OFF);
    float4 v[4];
    #pragma unroll
    for (int i = 0; i < 4; i++) v[i] = x4[row * 256 + i * 64 + lane];
    #pragma unroll
    for (int p = 0; p < 8; p++) {
      #pragma unroll
      for (int i = 0; i < 4; i++) {
        float4 d = dp4[p * 16384 + wr * 256 + i * 64 + lane];
        v[i].x += d.x; v[i].y += d.y; v[i].z += d.z; v[i].w += d.w;
      }
    }
    float sum = 0.f, ss = 0.f;
    #pragma unroll
    for (int i = 0; i < 4; i++) {
      sum += v[i].x + v[i].y + v[i].z + v[i].w;
      ss  += v[i].x * v[i].x + v[i].y * v[i].y + v[i].z * v[i].z + v[i].w * v[i].w;
    }
    #pragma unroll
    for (int off = 1; off < 64; off <<= 1) {
      sum += __shfl_xor(sum, off);
      ss  += __shfl_xor(ss, off);
    }
    float mu   = sum * (1.f / 1024.f);
    float rstd = rsqrtf(ss * (1.f / 1024.f) - mu * mu + 1e-5f);
    #pragma unroll
    for (int i = 0; i < 4; i++) {
      float4 g  = g4[i * 64 + lane];
      float4 be = b4[i * 64 + lane];
      float4 o;
      o.x = (v[i].x - mu) * rstd * g.x + be.x;
      o.y = (v[i].y - mu) * rstd * g.y + be.y;
      o.z = (v[i].z - mu) * rstd * g.z + be.z;
      o.w = (v[i].w - mu) * rstd * g.w + be.w;
      out4[row * 256 + i * 64 + lane] = o;
    }
  }
}

// ===========================================================================
// Legacy 5-kernel fallback (identical to R2 best) — used only if cooperative
// launch is unavailable.
// ===========================================================================

__global__ __launch_bounds__(256) void zero_ws(float4* __restrict__ ws) {
  ws[blockIdx.x * 256 + threadIdx.x] = make_float4(0.f, 0.f, 0.f, 0.f);
}

__global__ __launch_bounds__(256, 4) void proj_kernel(
    const float* __restrict__ x,
    const float* __restrict__ Wq, const float* __restrict__ Wk,
    const float* __restrict__ Wkp, const float* __restrict__ Wv,
    float* __restrict__ Y) {
  __shared__ float xs[64 * 65];
  const int tid = threadIdx.x;
  const int z    = blockIdx.x >> 4;
  const int col0 = (blockIdx.x & 15) * 64;
  const int k0   = blockIdx.y * 64;
  const float* __restrict__ W =
      (z == 0) ? Wq : ((z == 1) ? Wk : ((z == 2) ? Wkp : Wv));

  #pragma unroll
  for (int i = 0; i < 4; i++) {
    int e = i * 256 + tid;
    int r = e >> 4, q = e & 15;
    int b = r >> 5, t = r & 31;
    float4 v = *(const float4*)(x + ((b * 2048 + 2016 + t) * 1024 + k0 + q * 4));
    xs[(q * 4 + 0) * 65 + r] = v.x;
    xs[(q * 4 + 1) * 65 + r] = v.y;
    xs[(q * 4 + 2) * 65 + r] = v.z;
    xs[(q * 4 + 3) * 65 + r] = v.w;
  }
  __syncthreads();

  const int wave = __builtin_amdgcn_readfirstlane(tid >> 6);
  const int lane = tid & 63;
  const float* __restrict__ Wt = W + (size_t)k0 * 1024 + col0 + wave * 16;

  float acc[16];
  #pragma unroll
  for (int c = 0; c < 16; c++) acc[c] = 0.f;

  #pragma unroll 4
  for (int kk = 0; kk < 64; kk++) {
    float xv = xs[kk * 65 + lane];
    const float* __restrict__ wrow = Wt + kk * 1024;
    #pragma unroll
    for (int c = 0; c < 16; c++) acc[c] = fmaf(xv, wrow[c], acc[c]);
  }

  __syncthreads();
  #pragma unroll
  for (int c = 0; c < 16; c++) xs[lane * 65 + wave * 16 + c] = acc[c];
  __syncthreads();
  float* __restrict__ Yo = Y + z * 65536 + col0;
  #pragma unroll
  for (int i = 0; i < 16; i++) {
    int r = wave * 16 + i;
    atomicAdd(Yo + r * 1024 + lane, xs[r * 65 + lane]);
  }
}

__global__ __launch_bounds__(256) void attn_kernel(
    const float* __restrict__ Y, float* __restrict__ Zout) {
  __shared__ float Kn[32 * XS], Kp[32 * XS], Vs[32 * XS];
  __shared__ float Pt[4][32 * 33];
  __shared__ float qs[4][64];
  const int tid = threadIdx.x;
  const int wave = tid >> 6, lane = tid & 63;
  const int h = blockIdx.y, b = blockIdx.z;

  #pragma unroll
  for (int i = 0; i < 8; i++) {
    int e = i * 256 + tid;
    int row = e >> 6, d = e & 63;
    int src = (b * 32 + row) * 1024 + h * 64 + d;
    Kn[row * XS + d] = Y[YK_OFF + src];
    Kp[row * XS + d] = Y[YKP_OFF + src];
    Vs[row * XS + d] = Y[YV_OFF + src];
  }
  __syncthreads();

  for (int rr = 0; rr < 8; rr++) {
    int row = wave * 8 + rr;
    float kv = Kn[row * XS + lane];
    float s2 = kv * kv;
    #pragma unroll
    for (int off = 1; off < 64; off <<= 1) s2 += __shfl_xor(s2, off);
    Kn[row * XS + lane] = kv * (1.f / (sqrtf(s2) + 1e-7f));
    float pv = Kp[row * XS + lane];
    float p2 = pv * pv;
    #pragma unroll
    for (int off = 1; off < 64; off <<= 1) p2 += __shfl_xor(p2, off);
    Kp[row * XS + lane] = pv * (1.f / (sqrtf(p2) + 1e-7f));
  }
  __syncthreads();

  const int m = blockIdx.x * 4 + wave;
  const int r = b * 32 + m;

  float q = Y[YQ_OFF + r * 1024 + h * 64 + lane];
  float q2 = q * q;
  #pragma unroll
  for (int off = 1; off < 64; off <<= 1) q2 += __shfl_xor(q2, off);
  q *= (1.f / (sqrtf(q2) + 1e-7f));
  qs[wave][lane] = q;
  __builtin_amdgcn_wave_barrier();

  const int lj = lane >> 3, lk = lane & 7;
  float acc[4][4];
  #pragma unroll
  for (int a = 0; a < 4; a++)
    #pragma unroll
    for (int c = 0; c < 4; c++) acc[a][c] = 0.f;

  const float* qw = qs[wave];
  for (int dq = 0; dq < 16; dq++) {
    float4 q4 = *(const float4*)(qw + dq * 4);
    float4 t4[4], kp4[4];
    #pragma unroll
    for (int tj = 0; tj < 4; tj++) {
      float4 kv = *(const float4*)(Kn + (lj * 4 + tj) * XS + dq * 4);
      t4[tj].x = q4.x * kv.x; t4[tj].y = q4.y * kv.y;
      t4[tj].z = q4.z * kv.z; t4[tj].w = q4.w * kv.w;
    }
    #pragma unroll
    for (int tk = 0; tk < 4; tk++)
      kp4[tk] = *(const float4*)(Kp + (lk * 4 + tk) * XS + dq * 4);
    #pragma unroll
    for (int tj = 0; tj < 4; tj++)
      #pragma unroll
      for (int tk = 0; tk < 4; tk++)
        acc[tj][tk] += t4[tj].x * kp4[tk].x + t4[tj].y * kp4[tk].y
                     + t4[tj].z * kp4[tk].z + t4[tj].w * kp4[tk].w;
  }

  float amax = -1e30f;
  #pragma unroll
  for (int tj = 0; tj < 4; tj++)
    #pragma unroll
    for (int tk = 0; tk < 4; tk++) {
      int j = lj * 4 + tj, k = lk * 4 + tk;
      if (j <= m && k <= m) amax = fmaxf(amax, acc[tj][tk] * 0.125f);
    }
  #pragma unroll
  for (int off = 1; off < 64; off <<= 1) amax = fmaxf(amax, __shfl_xor(amax, off));

  float lsum = 0.f;
  float* ptw = Pt[wave];
  #pragma unroll
  for (int tj = 0; tj < 4; tj++)
    #pragma unroll
    for (int tk = 0; tk < 4; tk++) {
      int j = lj * 4 + tj, k = lk * 4 + tk;
      float e = 0.f;
      if (j <= m && k <= m) e = __expf(acc[tj][tk] * 0.125f - amax);
      lsum += e;
      ptw[k * 33 + j] = e;
    }
  #pragma unroll
  for (int off = 1; off < 64; off <<= 1) lsum += __shfl_xor(lsum, off);
  float inv = 1.f / lsum;
  __builtin_amdgcn_wave_barrier();

  float vreg[32];
  #pragma unroll
  for (int k = 0; k < 32; k++) vreg[k] = Vs[k * XS + lane];
  float zacc = 0.f;
  for (int k = 0; k <= m; k++) {
    float g = 0.f;
    #pragma unroll
    for (int j = 0; j < 32; j++) g += ptw[k * 33 + j] * vreg[j];
    zacc += g * vreg[k];
  }
  Zout[r * 1024 + h * 64 + lane] = zacc * inv;
}

__global__ __launch_bounds__(256, 4) void wo_kernel(
    const float* __restrict__ Zr, const float* __restrict__ Wo,
    float* __restrict__ delta) {
  __shared__ float xs[64 * 65];
  const int tid = threadIdx.x;
  const int col0 = blockIdx.x * 64;
  const int k0   = blockIdx.y * 32;

  #pragma unroll
  for (int i = 0; i < 2; i++) {
    int e = i * 256 + tid;
    int r = e >> 3, q = e & 7;
    float4 v = *(const float4*)(Zr + r * 1024 + k0 + q * 4);
    xs[(q * 4 + 0) * 65 + r] = v.x;
    xs[(q * 4 + 1) * 65 + r] = v.y;
    xs[(q * 4 + 2) * 65 + r] = v.z;
    xs[(q * 4 + 3) * 65 + r] = v.w;
  }
  __syncthreads();

  const int wave = __builtin_amdgcn_readfirstlane(tid >> 6);
  const int lane = tid & 63;
  const float* __restrict__ Wt = Wo + (size_t)k0 * 1024 + col0 + wave * 16;

  float acc[16];
  #pragma unroll
  for (int c = 0; c < 16; c++) acc[c] = 0.f;

  #pragma unroll 4
  for (int kk = 0; kk < 32; kk++) {
    float xv = xs[kk * 65 + lane];
    const float* __restrict__ wrow = Wt + kk * 1024;
    #pragma unroll
    for (int c = 0; c < 16; c++) acc[c] = fmaf(xv, wrow[c], acc[c]);
  }

  __syncthreads();
  #pragma unroll
  for (int c = 0; c < 16; c++) xs[lane * 65 + wave * 16 + c] = acc[c];
  __syncthreads();
  #pragma unroll
  for (int i = 0; i < 16; i++) {
    int r = wave * 16 + i;
    atomicAdd(delta + r * 1024 + col0 + lane, xs[r * 65 + lane]);
  }
}

__global__ __launch_bounds__(256, 4) void ln_kernel(
    const float4* __restrict__ x4, const float4* __restrict__ delta4,
    const float4* __restrict__ g4, const float4* __restrict__ b4,
    float4* __restrict__ out4) {
  const int tid = threadIdx.x;
  const int wave = tid >> 6, lane = tid & 63;
  const int row = blockIdx.x * 4 + wave;
  const int b = row >> 11, s = row & 2047;

  float4 v[4];
  #pragma unroll
  for (int i = 0; i < 4; i++) v[i] = x4[row * 256 + i * 64 + lane];
  if (s >= 2016) {
    int drow = b * 32 + (s - 2016);
    #pragma unroll
    for (int i = 0; i < 4; i++) {
      float4 d = delta4[drow * 256 + i * 64 + lane];
      v[i].x += d.x; v[i].y += d.y; v[i].z += d.z; v[i].w += d.w;
    }
  }
  float sum = 0.f, ss = 0.f;
  #pragma unroll
  for (int i = 0; i < 4; i++) {
    sum += v[i].x + v[i].y + v[i].z + v[i].w;
    ss  += v[i].x * v[i].x + v[i].y * v[i].y + v[i].z * v[i].z + v[i].w * v[i].w;
  }
  #pragma unroll
  for (int off = 1; off < 64; off <<= 1) {
    sum += __shfl_xor(sum, off);
    ss  += __shfl_xor(ss, off);
  }
  float mu   = sum * (1.f / 1024.f);
  float var  = ss * (1.f / 1024.f) - mu * mu;
  float rstd = rsqrtf(var + 1e-5f);

  #pragma unroll
  for (int i = 0; i < 4; i++) {
    float4 g = g4[i * 64 + lane];
    float4 be = b4[i * 64 + lane];
    float4 o;
    o.x = (v[i].x - mu) * rstd * g.x + be.x;
    o.y = (v[i].y - mu) * rstd * g.y + be.y;
    o.z = (v[i].z - mu) * rstd * g.z + be.z;
    o.w = (v[i].w - mu) * rstd * g.w + be.w;
    out4[row * 256 + i * 64 + lane] = o;
  }
}

// ---------------------------------------------------------------------------
extern "C" void kernel_launch(void* const* d_in, const int* in_sizes, int n_in,
                              void* d_out, int out_size, void* d_ws, size_t ws_size,
                              hipStream_t stream) {
  const float* x   = (const float*)d_in[0];
  const float* Wq  = (const float*)d_in[1];
  const float* Wk  = (const float*)d_in[2];
  const float* Wv  = (const float*)d_in[3];  // NB: dict order, W_V before W_Kp
  const float* Wkp = (const float*)d_in[4];
  const float* Wo  = (const float*)d_in[5];
  const float* gam = (const float*)d_in[6];
  const float* bet = (const float*)d_in[7];
  float* out = (float*)d_out;
  float* ws  = (float*)d_ws;

  // One-time capability check (host-side query, graph-capture safe).
  static int coop_ok = -1;
  if (coop_ok < 0) {
    int dev = 0;
    (void)hipGetDevice(&dev);
    int attr = 0;
    hipError_t qe = hipDeviceGetAttribute(&attr, hipDeviceAttributeCooperativeLaunch, dev);
    coop_ok = (qe == hipSuccess && attr != 0) ? 1 : 0;
  }

  hipError_t err = hipErrorUnknown;
  if (coop_ok == 1 && ws_size >= (size_t)FUSED_WS_FLOATS * sizeof(float)) {
    void* kargs[] = {(void*)&x,  (void*)&Wq, (void*)&Wk,  (void*)&Wkp,
                     (void*)&Wv, (void*)&Wo, (void*)&gam, (void*)&bet,
                     (void*)&out, (void*)&ws};
    err = hipLaunchCooperativeKernel((const void*)fused_kernel, dim3(512),
                                     dim3(256), kargs, 0, stream);
  }

  if (err != hipSuccess) {
    (void)hipGetLastError();  // clear
    // Legacy 5-kernel path.
    hipLaunchKernelGGL(zero_ws, dim3(WS_FLOATS / 1024), dim3(256), 0, stream,
                       (float4*)ws);
    hipLaunchKernelGGL(proj_kernel, dim3(64, 16), dim3(256), 0, stream,
                       x, Wq, Wk, Wkp, Wv, ws);
    hipLaunchKernelGGL(attn_kernel, dim3(8, 16, 2), dim3(256), 0, stream,
                       ws, ws + Z_OFF);
    hipLaunchKernelGGL(wo_kernel, dim3(16, 32), dim3(256), 0, stream,
                       ws + Z_OFF, Wo, ws + DELTA_OFF);
    hipLaunchKernelGGL(ln_kernel, dim3(1024), dim3(256), 0, stream,
                       (const float4*)x, (const float4*)(ws + DELTA_OFF),
                       (const float4*)gam, (const float4*)bet, (float4*)out);
  }
}

// Round 3
// 136.445 us; speedup vs baseline: 2.3698x; 2.3698x over previous
//
#include <hip/hip_runtime.h>
#include <math.h>

// ---------------------------------------------------------------------------
// TwoSimplicialAttention, MI355X. Structure exploit: mask kills attention for
// all s < 2016; only last 32 rows/batch (64 rows) carry attention. Everything
// else is out = LayerNorm(x).
//
// R5 = R4 with the W-staging bug fixed (W tile is 64x64 = 4096 floats; R4
// staged only 1024 -> rows 16..63 were garbage). GEMMs (proj, wo) stage W in
// LDS via coalesced float4 loads and read wave-uniform ds_read_b128
// broadcasts in the FMA loop — removes the per-iteration s_load_dwordx16
// latency chain. No atomics / no zero pass: k-split partials.
// ---------------------------------------------------------------------------

#define XS 68   // attn LDS pad

// ===== ws layout (floats); harness ws is ~256 MB (fillBuffer 262144 KB) ====
#define YP_STR   262144                    // one Y partial: [64][4096]
#define NKS_P    8                         // proj k-splits
#define ZF_OFF   (NKS_P * YP_STR)          // [64][1024]  = 2097152
#define DP_OFF   (ZF_OFF + 65536)          // delta partials
#define DP_STR   65536                     // one delta partial: [64][1024]
#define NKS_W    16                        // wo k-splits

// ---- kernel A: Y partials[8][64][4096] = x_win @ [W_Q|W_K|W_Kp|W_V] -------
// grid (64 colblocks of 64 cols, 8 ksplits of 128 k) = 512 blocks.
// lane = row. W tile staged in LDS (vector loads), FMA loop reads uniform
// ds_read_b128 broadcasts. Partial stores, no atomics.
__global__ __launch_bounds__(256, 4) void proj_kernel(
    const float* __restrict__ x,
    const float* __restrict__ Wq, const float* __restrict__ Wk,
    const float* __restrict__ Wkp, const float* __restrict__ Wv,
    float* __restrict__ Y) {
  __shared__ float xs[64 * 65];      // [kk][r]
  __shared__ float wl[64 * 68];      // [kk][c]
  const int tid  = threadIdx.x;
  const int cb   = blockIdx.x;                    // 0..63 over 4096 cols
  const int ks   = blockIdx.y;                    // 0..7
  const int col0 = cb * 64;
  const int z    = cb >> 4;                       // which W matrix
  const int colz = col0 & 1023;
  const float* __restrict__ W =
      (z == 0) ? Wq : ((z == 1) ? Wk : ((z == 2) ? Wkp : Wv));

  const int wave = __builtin_amdgcn_readfirstlane(tid >> 6);  // uniform
  const int lane = tid & 63;                                  // = row

  float acc[16];
  #pragma unroll
  for (int c = 0; c < 16; c++) acc[c] = 0.f;

  for (int cc = 0; cc < 2; cc++) {               // 2 chunks of 64 k
    const int kb = ks * 128 + cc * 64;
    // stage x^T tile: 64 rows x 64 k (coalesced float4)
    #pragma unroll
    for (int i = 0; i < 4; i++) {
      int e = i * 256 + tid;                     // r(64) x quad(16)
      int r = e >> 4, q = e & 15;
      int b = r >> 5, t = r & 31;
      float4 v = *(const float4*)(x + ((b * 2048 + 2016 + t) * 1024 + kb + q * 4));
      xs[(q * 4 + 0) * 65 + r] = v.x;
      xs[(q * 4 + 1) * 65 + r] = v.y;
      xs[(q * 4 + 2) * 65 + r] = v.z;
      xs[(q * 4 + 3) * 65 + r] = v.w;
    }
    // stage W tile: 64 k x 64 cols (coalesced float4; FULL 64 rows)
    #pragma unroll
    for (int i = 0; i < 4; i++) {
      int e = i * 256 + tid;
      int r = e >> 4, q = e & 15;                // k-row 0..63, col-quad
      float4 v = *(const float4*)(W + (size_t)(kb + r) * 1024 + colz + q * 4);
      float* d = wl + r * 68 + q * 4;
      d[0] = v.x; d[1] = v.y; d[2] = v.z; d[3] = v.w;
    }
    __syncthreads();

    const float* __restrict__ wbase = wl + wave * 16;
    #pragma unroll 4
    for (int kk = 0; kk < 64; kk++) {
      float xv = xs[kk * 65 + lane];             // conflict-free vector read
      const float* __restrict__ wrow = wbase + kk * 68;  // uniform -> b128 bcast
      #pragma unroll
      for (int c = 0; c < 16; c++) acc[c] = fmaf(xv, wrow[c], acc[c]);
    }
    __syncthreads();
  }

  // transpose through LDS for coalesced partial stores
  #pragma unroll
  for (int c = 0; c < 16; c++) xs[lane * 65 + wave * 16 + c] = acc[c];
  __syncthreads();
  float* __restrict__ Yo = Y + ks * YP_STR + col0;
  #pragma unroll
  for (int i = 0; i < 16; i++) {
    int r = wave * 16 + i;
    Yo[r * 4096 + lane] = xs[r * 65 + lane];
  }
}

// ---- kernel B: attention for the 64 window rows (sums 8 Y partials) -------
__global__ __launch_bounds__(256) void attn_kernel(
    const float* __restrict__ Y, float* __restrict__ Zout) {
  __shared__ float Kn[32 * XS], Kp[32 * XS], Vs[32 * XS];
  __shared__ float Pt[4][32 * 33];
  __shared__ float qs[4][64];
  const int tid = threadIdx.x;
  const int wave = tid >> 6, lane = tid & 63;
  const int h = blockIdx.y, b = blockIdx.z;

  #pragma unroll
  for (int i = 0; i < 8; i++) {      // stage K/Kp/V, summing 8 ksplit partials
    int e = i * 256 + tid;
    int row = e >> 6, d = e & 63;
    int src = (b * 32 + row) * 4096 + h * 64 + d;
    float kn = 0.f, kp = 0.f, vv = 0.f;
    #pragma unroll
    for (int p = 0; p < NKS_P; p++) {
      const float* Yp = Y + p * YP_STR + src;
      kn += Yp[1024]; kp += Yp[2048]; vv += Yp[3072];
    }
    Kn[row * XS + d] = kn; Kp[row * XS + d] = kp; Vs[row * XS + d] = vv;
  }
  __syncthreads();

  for (int rr = 0; rr < 8; rr++) {   // l2-normalize K, Kp rows
    int row = wave * 8 + rr;
    float kv = Kn[row * XS + lane];
    float s2 = kv * kv;
    #pragma unroll
    for (int off = 1; off < 64; off <<= 1) s2 += __shfl_xor(s2, off);
    Kn[row * XS + lane] = kv * (1.f / (sqrtf(s2) + 1e-7f));
    float pv = Kp[row * XS + lane];
    float p2 = pv * pv;
    #pragma unroll
    for (int off = 1; off < 64; off <<= 1) p2 += __shfl_xor(p2, off);
    Kp[row * XS + lane] = pv * (1.f / (sqrtf(p2) + 1e-7f));
  }
  __syncthreads();

  const int m = blockIdx.x * 4 + wave;
  const int r = b * 32 + m;

  float q = 0.f;
  #pragma unroll
  for (int p = 0; p < NKS_P; p++) q += Y[p * YP_STR + r * 4096 + h * 64 + lane];
  float q2 = q * q;
  #pragma unroll
  for (int off = 1; off < 64; off <<= 1) q2 += __shfl_xor(q2, off);
  q *= (1.f / (sqrtf(q2) + 1e-7f));
  qs[wave][lane] = q;
  __builtin_amdgcn_wave_barrier();

  const int lj = lane >> 3, lk = lane & 7;
  float acc[4][4];
  #pragma unroll
  for (int a = 0; a < 4; a++)
    #pragma unroll
    for (int c = 0; c < 4; c++) acc[a][c] = 0.f;

  const float* qw = qs[wave];
  for (int dq = 0; dq < 16; dq++) {
    float4 q4 = *(const float4*)(qw + dq * 4);
    float4 t4[4], kp4[4];
    #pragma unroll
    for (int tj = 0; tj < 4; tj++) {
      float4 kv = *(const float4*)(Kn + (lj * 4 + tj) * XS + dq * 4);
      t4[tj].x = q4.x * kv.x; t4[tj].y = q4.y * kv.y;
      t4[tj].z = q4.z * kv.z; t4[tj].w = q4.w * kv.w;
    }
    #pragma unroll
    for (int tk = 0; tk < 4; tk++)
      kp4[tk] = *(const float4*)(Kp + (lk * 4 + tk) * XS + dq * 4);
    #pragma unroll
    for (int tj = 0; tj < 4; tj++)
      #pragma unroll
      for (int tk = 0; tk < 4; tk++)
        acc[tj][tk] += t4[tj].x * kp4[tk].x + t4[tj].y * kp4[tk].y
                     + t4[tj].z * kp4[tk].z + t4[tj].w * kp4[tk].w;
  }

  float amax = -1e30f;
  #pragma unroll
  for (int tj = 0; tj < 4; tj++)
    #pragma unroll
    for (int tk = 0; tk < 4; tk++) {
      int j = lj * 4 + tj, k = lk * 4 + tk;
      if (j <= m && k <= m) amax = fmaxf(amax, acc[tj][tk] * 0.125f);
    }
  #pragma unroll
  for (int off = 1; off < 64; off <<= 1) amax = fmaxf(amax, __shfl_xor(amax, off));

  float lsum = 0.f;
  float* ptw = Pt[wave];
  #pragma unroll
  for (int tj = 0; tj < 4; tj++)
    #pragma unroll
    for (int tk = 0; tk < 4; tk++) {
      int j = lj * 4 + tj, k = lk * 4 + tk;
      float e = 0.f;
      if (j <= m && k <= m) e = __expf(acc[tj][tk] * 0.125f - amax);
      lsum += e;
      ptw[k * 33 + j] = e;
    }
  #pragma unroll
  for (int off = 1; off < 64; off <<= 1) lsum += __shfl_xor(lsum, off);
  float inv = 1.f / lsum;
  __builtin_amdgcn_wave_barrier();

  float vreg[32];
  #pragma unroll
  for (int k = 0; k < 32; k++) vreg[k] = Vs[k * XS + lane];
  float zacc = 0.f;
  for (int k = 0; k <= m; k++) {
    float g = 0.f;
    #pragma unroll
    for (int j = 0; j < 32; j++) g += ptw[k * 33 + j] * vreg[j];
    zacc += g * vreg[k];
  }
  Zout[r * 1024 + h * 64 + lane] = zacc * inv;
}

// ---- kernel C: delta partials[16][64][1024] = Z @ W_O ---------------------
// grid (16 colblocks, 16 ksplits of 64 k) = 256 blocks. Same LDS-W scheme.
__global__ __launch_bounds__(256, 4) void wo_kernel(
    const float* __restrict__ Zr, const float* __restrict__ Wo,
    float* __restrict__ Dp) {
  __shared__ float xs[64 * 65];
  __shared__ float wl[64 * 68];
  const int tid  = threadIdx.x;
  const int col0 = blockIdx.x * 64;
  const int ks   = blockIdx.y;
  const int kb   = ks * 64;

  const int wave = __builtin_amdgcn_readfirstlane(tid >> 6);
  const int lane = tid & 63;        // = Z row

  // stage Z^T tile: 64 rows x 64 k
  #pragma unroll
  for (int i = 0; i < 4; i++) {
    int e = i * 256 + tid;
    int r = e >> 4, q = e & 15;
    float4 v = *(const float4*)(Zr + r * 1024 + kb + q * 4);
    xs[(q * 4 + 0) * 65 + r] = v.x;
    xs[(q * 4 + 1) * 65 + r] = v.y;
    xs[(q * 4 + 2) * 65 + r] = v.z;
    xs[(q * 4 + 3) * 65 + r] = v.w;
  }
  // stage Wo tile: 64 k x 64 cols (FULL 64 rows)
  #pragma unroll
  for (int i = 0; i < 4; i++) {
    int e = i * 256 + tid;
    int r = e >> 4, q = e & 15;
    float4 v = *(const float4*)(Wo + (size_t)(kb + r) * 1024 + col0 + q * 4);
    float* d = wl + r * 68 + q * 4;
    d[0] = v.x; d[1] = v.y; d[2] = v.z; d[3] = v.w;
  }
  __syncthreads();

  float acc[16];
  #pragma unroll
  for (int c = 0; c < 16; c++) acc[c] = 0.f;

  const float* __restrict__ wbase = wl + wave * 16;
  #pragma unroll 4
  for (int kk = 0; kk < 64; kk++) {
    float xv = xs[kk * 65 + lane];
    const float* __restrict__ wrow = wbase + kk * 68;   // uniform -> b128 bcast
    #pragma unroll
    for (int c = 0; c < 16; c++) acc[c] = fmaf(xv, wrow[c], acc[c]);
  }

  __syncthreads();
  #pragma unroll
  for (int c = 0; c < 16; c++) xs[lane * 65 + wave * 16 + c] = acc[c];
  __syncthreads();
  float* __restrict__ D = Dp + ks * DP_STR + col0;
  #pragma unroll
  for (int i = 0; i < 16; i++) {
    int r = wave * 16 + i;
    D[r * 1024 + lane] = xs[r * 65 + lane];
  }
}

// ---- kernel D: out = LayerNorm(x [+ sum of 16 delta partials]) ------------
__global__ __launch_bounds__(256, 4) void ln_kernel(
    const float4* __restrict__ x4, const float4* __restrict__ dp4,
    const float4* __restrict__ g4, const float4* __restrict__ b4,
    float4* __restrict__ out4) {
  const int tid = threadIdx.x;
  const int wave = tid >> 6, lane = tid & 63;
  const int row = blockIdx.x * 4 + wave;       // 0..4095
  const int b = row >> 11, s = row & 2047;

  float4 v[4];
  #pragma unroll
  for (int i = 0; i < 4; i++) v[i] = x4[row * 256 + i * 64 + lane];
  if (s >= 2016) {                             // wave-uniform branch
    int drow = b * 32 + (s - 2016);
    #pragma unroll
    for (int p = 0; p < NKS_W; p++) {
      #pragma unroll
      for (int i = 0; i < 4; i++) {
        float4 d = dp4[p * 16384 + drow * 256 + i * 64 + lane];
        v[i].x += d.x; v[i].y += d.y; v[i].z += d.z; v[i].w += d.w;
      }
    }
  }
  float sum = 0.f, ss = 0.f;
  #pragma unroll
  for (int i = 0; i < 4; i++) {
    sum += v[i].x + v[i].y + v[i].z + v[i].w;
    ss  += v[i].x * v[i].x + v[i].y * v[i].y + v[i].z * v[i].z + v[i].w * v[i].w;
  }
  #pragma unroll
  for (int off = 1; off < 64; off <<= 1) {
    sum += __shfl_xor(sum, off);
    ss  += __shfl_xor(ss, off);
  }
  float mu   = sum * (1.f / 1024.f);
  float var  = ss * (1.f / 1024.f) - mu * mu;
  float rstd = rsqrtf(var + 1e-5f);

  #pragma unroll
  for (int i = 0; i < 4; i++) {
    float4 g = g4[i * 64 + lane];
    float4 be = b4[i * 64 + lane];
    float4 o;
    o.x = (v[i].x - mu) * rstd * g.x + be.x;
    o.y = (v[i].y - mu) * rstd * g.y + be.y;
    o.z = (v[i].z - mu) * rstd * g.z + be.z;
    o.w = (v[i].w - mu) * rstd * g.w + be.w;
    out4[row * 256 + i * 64 + lane] = o;
  }
}

// ---------------------------------------------------------------------------
extern "C" void kernel_launch(void* const* d_in, const int* in_sizes, int n_in,
                              void* d_out, int out_size, void* d_ws, size_t ws_size,
                              hipStream_t stream) {
  const float* x   = (const float*)d_in[0];
  const float* Wq  = (const float*)d_in[1];
  const float* Wk  = (const float*)d_in[2];
  const float* Wv  = (const float*)d_in[3];  // NB: dict order, W_V before W_Kp
  const float* Wkp = (const float*)d_in[4];
  const float* Wo  = (const float*)d_in[5];
  const float* gam = (const float*)d_in[6];
  const float* bet = (const float*)d_in[7];
  float* out = (float*)d_out;
  float* ws  = (float*)d_ws;   // needs 12.9 MB (harness provides ~256 MB)

  hipLaunchKernelGGL(proj_kernel, dim3(64, NKS_P), dim3(256), 0, stream,
                     x, Wq, Wk, Wkp, Wv, ws);
  hipLaunchKernelGGL(attn_kernel, dim3(8, 16, 2), dim3(256), 0, stream,
                     ws, ws + ZF_OFF);
  hipLaunchKernelGGL(wo_kernel, dim3(16, NKS_W), dim3(256), 0, stream,
                     ws + ZF_OFF, Wo, ws + DP_OFF);
  hipLaunchKernelGGL(ln_kernel, dim3(1024), dim3(256), 0, stream,
                     (const float4*)x, (const float4*)(ws + DP_OFF),
                     (const float4*)gam, (const float4*)bet, (float4*)out);
}

// Round 4
// 128.834 us; speedup vs baseline: 2.5098x; 1.0591x over previous
//
#include <hip/hip_runtime.h>
#include <math.h>

// ---------------------------------------------------------------------------
// TwoSimplicialAttention, MI355X. Structure exploit: mask kills attention for
// all s < 2016; only last 32 rows/batch (64 rows) carry attention. Everything
// else is out = LayerNorm(x).
//
// R6: (a) proj/wo inner loop rewritten as 4x4 register-tiled outer product:
// per k-step each thread reads ONE float4 of x-rows + ONE float4 of W-cols
// from LDS and does 16 FMAs (128 LDS instrs/thread vs R5's 640 — R5 profile
// showed proj LDS-pipe-bound at 31.5us, 10x its 3.4us VALU floor). Epilogue
// stores acc directly as coalesced float4 (no LDS transpose).
// (b) The dependency-free LayerNorm of the 4032 non-window rows is folded
// into the proj dispatch as extra blocks (overlaps with LDS-bound proj);
// the final dispatch only handles the 64 window rows.
// ---------------------------------------------------------------------------

#define XS 68   // attn LDS pad
#define WS 68   // gemm LDS stride (float4-aligned, decent bank spread)

// ===== ws layout (floats); harness ws is ~256 MB ====
#define YP_STR   262144                    // one Y partial: [64][4096]
#define NKS_P    8                         // proj k-splits
#define ZF_OFF   (NKS_P * YP_STR)          // [64][1024]  = 2097152
#define DP_OFF   (ZF_OFF + 65536)          // delta partials
#define DP_STR   65536                     // one delta partial: [64][1024]
#define NKS_W    16                        // wo k-splits

// ---------------------------------------------------------------------------
// LayerNorm of one row (no delta), one wave per row.
__device__ __forceinline__ void ln_row(
    const float4* __restrict__ x4, const float4* __restrict__ g4,
    const float4* __restrict__ b4, float4* __restrict__ out4,
    int row, int lane) {
  float4 v[4];
  #pragma unroll
  for (int i = 0; i < 4; i++) v[i] = x4[row * 256 + i * 64 + lane];
  float sum = 0.f, ss = 0.f;
  #pragma unroll
  for (int i = 0; i < 4; i++) {
    sum += v[i].x + v[i].y + v[i].z + v[i].w;
    ss  += v[i].x * v[i].x + v[i].y * v[i].y + v[i].z * v[i].z + v[i].w * v[i].w;
  }
  #pragma unroll
  for (int off = 1; off < 64; off <<= 1) {
    sum += __shfl_xor(sum, off);
    ss  += __shfl_xor(ss, off);
  }
  float mu   = sum * (1.f / 1024.f);
  float rstd = rsqrtf(ss * (1.f / 1024.f) - mu * mu + 1e-5f);
  #pragma unroll
  for (int i = 0; i < 4; i++) {
    float4 g  = g4[i * 64 + lane];
    float4 be = b4[i * 64 + lane];
    float4 o;
    o.x = (v[i].x - mu) * rstd * g.x + be.x;
    o.y = (v[i].y - mu) * rstd * g.y + be.y;
    o.z = (v[i].z - mu) * rstd * g.z + be.z;
    o.w = (v[i].w - mu) * rstd * g.w + be.w;
    out4[row * 256 + i * 64 + lane] = o;
  }
}

// ---- kernel A: proj partials + non-window LayerNorm -----------------------
// bid < 512: Y partials[8][64][4096] = x_win @ [W_Q|W_K|W_Kp|W_V]
//   (64 colblocks of 64 cols) x (8 ksplits of 128 k); 4x4 register tile.
// bid >= 512: 448 blocks x 4 waves grid-stride LayerNorm over 4032 rows.
__global__ __launch_bounds__(256, 4) void proj_ln_kernel(
    const float* __restrict__ x,
    const float* __restrict__ Wq, const float* __restrict__ Wk,
    const float* __restrict__ Wkp, const float* __restrict__ Wv,
    const float* __restrict__ gam, const float* __restrict__ bet,
    float* __restrict__ Y, float* __restrict__ out) {
  __shared__ float xs[64 * WS];      // [kk][row], rows contiguous
  __shared__ float wl[64 * WS];      // [kk][col], cols contiguous
  const int tid = threadIdx.x;
  const int bid = blockIdx.x;

  if (bid < 512) {
    const int cb   = bid & 63;                    // colblock over 4096 cols
    const int ks   = bid >> 6;                    // 0..7
    const int col0 = cb * 64;
    const int z    = cb >> 4;                     // which W matrix
    const int colz = col0 & 1023;
    const float* __restrict__ W =
        (z == 0) ? Wq : ((z == 1) ? Wk : ((z == 2) ? Wkp : Wv));
    const int tc = tid & 15, tr = tid >> 4;       // 16x16 thread grid

    float acc[4][4];
    #pragma unroll
    for (int i = 0; i < 4; i++)
      #pragma unroll
      for (int j = 0; j < 4; j++) acc[i][j] = 0.f;

    for (int cc = 0; cc < 2; cc++) {              // 2 chunks of 64 k
      const int kb = ks * 128 + cc * 64;
      #pragma unroll
      for (int i = 0; i < 4; i++) {
        int e = i * 256 + tid;
        int r = e >> 4, q = e & 15;               // r: row/k-row, q: quad
        int b = r >> 5, t = r & 31;
        // x^T tile: xs[kk][row]
        float4 v = *(const float4*)(x + ((b * 2048 + 2016 + t) * 1024 + kb + q * 4));
        xs[(q * 4 + 0) * WS + r] = v.x;
        xs[(q * 4 + 1) * WS + r] = v.y;
        xs[(q * 4 + 2) * WS + r] = v.z;
        xs[(q * 4 + 3) * WS + r] = v.w;
        // W tile: wl[kk][col] (row-major load, no transpose)
        float4 w = *(const float4*)(W + (size_t)(kb + r) * 1024 + colz + q * 4);
        *(float4*)(wl + r * WS + q * 4) = w;
      }
      __syncthreads();

      #pragma unroll 8
      for (int kk = 0; kk < 64; kk++) {
        float4 xv = *(const float4*)(xs + kk * WS + tr * 4);
        float4 wv = *(const float4*)(wl + kk * WS + tc * 4);
        acc[0][0] = fmaf(xv.x, wv.x, acc[0][0]);
        acc[0][1] = fmaf(xv.x, wv.y, acc[0][1]);
        acc[0][2] = fmaf(xv.x, wv.z, acc[0][2]);
        acc[0][3] = fmaf(xv.x, wv.w, acc[0][3]);
        acc[1][0] = fmaf(xv.y, wv.x, acc[1][0]);
        acc[1][1] = fmaf(xv.y, wv.y, acc[1][1]);
        acc[1][2] = fmaf(xv.y, wv.z, acc[1][2]);
        acc[1][3] = fmaf(xv.y, wv.w, acc[1][3]);
        acc[2][0] = fmaf(xv.z, wv.x, acc[2][0]);
        acc[2][1] = fmaf(xv.z, wv.y, acc[2][1]);
        acc[2][2] = fmaf(xv.z, wv.z, acc[2][2]);
        acc[2][3] = fmaf(xv.z, wv.w, acc[2][3]);
        acc[3][0] = fmaf(xv.w, wv.x, acc[3][0]);
        acc[3][1] = fmaf(xv.w, wv.y, acc[3][1]);
        acc[3][2] = fmaf(xv.w, wv.z, acc[3][2]);
        acc[3][3] = fmaf(xv.w, wv.w, acc[3][3]);
      }
      __syncthreads();
    }

    // direct coalesced float4 stores (thread owns rows tr*4.., cols tc*4..)
    float* __restrict__ Yo = Y + ks * YP_STR + col0;
    #pragma unroll
    for (int i = 0; i < 4; i++) {
      float4 o = make_float4(acc[i][0], acc[i][1], acc[i][2], acc[i][3]);
      *(float4*)(Yo + (tr * 4 + i) * 4096 + tc * 4) = o;
    }
  } else {
    // LayerNorm of the 4032 non-window rows (no dependencies)
    const int wave = tid >> 6, lane = tid & 63;
    const int gw = (bid - 512) * 4 + wave;        // 1792 LN waves
    const float4* x4 = (const float4*)x;
    const float4* g4 = (const float4*)gam;
    const float4* b4 = (const float4*)bet;
    float4* out4 = (float4*)out;
    for (int idx = gw; idx < 4032; idx += 1792) {
      int row = (idx < 2016) ? idx : idx + 32;
      ln_row(x4, g4, b4, out4, row, lane);
    }
  }
}

// ---- kernel B: attention for the 64 window rows (sums 8 Y partials) -------
__global__ __launch_bounds__(256) void attn_kernel(
    const float* __restrict__ Y, float* __restrict__ Zout) {
  __shared__ float Kn[32 * XS], Kp[32 * XS], Vs[32 * XS];
  __shared__ float Pt[4][32 * 33];
  __shared__ float qs[4][64];
  const int tid = threadIdx.x;
  const int wave = tid >> 6, lane = tid & 63;
  const int h = blockIdx.y, b = blockIdx.z;

  #pragma unroll
  for (int i = 0; i < 8; i++) {      // stage K/Kp/V, summing 8 ksplit partials
    int e = i * 256 + tid;
    int row = e >> 6, d = e & 63;
    int src = (b * 32 + row) * 4096 + h * 64 + d;
    float kn = 0.f, kp = 0.f, vv = 0.f;
    #pragma unroll
    for (int p = 0; p < NKS_P; p++) {
      const float* Yp = Y + p * YP_STR + src;
      kn += Yp[1024]; kp += Yp[2048]; vv += Yp[3072];
    }
    Kn[row * XS + d] = kn; Kp[row * XS + d] = kp; Vs[row * XS + d] = vv;
  }
  __syncthreads();

  for (int rr = 0; rr < 8; rr++) {   // l2-normalize K, Kp rows
    int row = wave * 8 + rr;
    float kv = Kn[row * XS + lane];
    float s2 = kv * kv;
    #pragma unroll
    for (int off = 1; off < 64; off <<= 1) s2 += __shfl_xor(s2, off);
    Kn[row * XS + lane] = kv * (1.f / (sqrtf(s2) + 1e-7f));
    float pv = Kp[row * XS + lane];
    float p2 = pv * pv;
    #pragma unroll
    for (int off = 1; off < 64; off <<= 1) p2 += __shfl_xor(p2, off);
    Kp[row * XS + lane] = pv * (1.f / (sqrtf(p2) + 1e-7f));
  }
  __syncthreads();

  const int m = blockIdx.x * 4 + wave;
  const int r = b * 32 + m;

  float q = 0.f;
  #pragma unroll
  for (int p = 0; p < NKS_P; p++) q += Y[p * YP_STR + r * 4096 + h * 64 + lane];
  float q2 = q * q;
  #pragma unroll
  for (int off = 1; off < 64; off <<= 1) q2 += __shfl_xor(q2, off);
  q *= (1.f / (sqrtf(q2) + 1e-7f));
  qs[wave][lane] = q;
  __builtin_amdgcn_wave_barrier();

  const int lj = lane >> 3, lk = lane & 7;
  float acc[4][4];
  #pragma unroll
  for (int a = 0; a < 4; a++)
    #pragma unroll
    for (int c = 0; c < 4; c++) acc[a][c] = 0.f;

  const float* qw = qs[wave];
  for (int dq = 0; dq < 16; dq++) {
    float4 q4 = *(const float4*)(qw + dq * 4);
    float4 t4[4], kp4[4];
    #pragma unroll
    for (int tj = 0; tj < 4; tj++) {
      float4 kv = *(const float4*)(Kn + (lj * 4 + tj) * XS + dq * 4);
      t4[tj].x = q4.x * kv.x; t4[tj].y = q4.y * kv.y;
      t4[tj].z = q4.z * kv.z; t4[tj].w = q4.w * kv.w;
    }
    #pragma unroll
    for (int tk = 0; tk < 4; tk++)
      kp4[tk] = *(const float4*)(Kp + (lk * 4 + tk) * XS + dq * 4);
    #pragma unroll
    for (int tj = 0; tj < 4; tj++)
      #pragma unroll
      for (int tk = 0; tk < 4; tk++)
        acc[tj][tk] += t4[tj].x * kp4[tk].x + t4[tj].y * kp4[tk].y
                     + t4[tj].z * kp4[tk].z + t4[tj].w * kp4[tk].w;
  }

  float amax = -1e30f;
  #pragma unroll
  for (int tj = 0; tj < 4; tj++)
    #pragma unroll
    for (int tk = 0; tk < 4; tk++) {
      int j = lj * 4 + tj, k = lk * 4 + tk;
      if (j <= m && k <= m) amax = fmaxf(amax, acc[tj][tk] * 0.125f);
    }
  #pragma unroll
  for (int off = 1; off < 64; off <<= 1) amax = fmaxf(amax, __shfl_xor(amax, off));

  float lsum = 0.f;
  float* ptw = Pt[wave];
  #pragma unroll
  for (int tj = 0; tj < 4; tj++)
    #pragma unroll
    for (int tk = 0; tk < 4; tk++) {
      int j = lj * 4 + tj, k = lk * 4 + tk;
      float e = 0.f;
      if (j <= m && k <= m) e = __expf(acc[tj][tk] * 0.125f - amax);
      lsum += e;
      ptw[k * 33 + j] = e;
    }
  #pragma unroll
  for (int off = 1; off < 64; off <<= 1) lsum += __shfl_xor(lsum, off);
  float inv = 1.f / lsum;
  __builtin_amdgcn_wave_barrier();

  float vreg[32];
  #pragma unroll
  for (int k = 0; k < 32; k++) vreg[k] = Vs[k * XS + lane];
  float zacc = 0.f;
  for (int k = 0; k <= m; k++) {
    float g = 0.f;
    #pragma unroll
    for (int j = 0; j < 32; j++) g += ptw[k * 33 + j] * vreg[j];
    zacc += g * vreg[k];
  }
  Zout[r * 1024 + h * 64 + lane] = zacc * inv;
}

// ---- kernel C: delta partials[16][64][1024] = Z @ W_O ---------------------
// grid (16 colblocks, 16 ksplits of 64 k); same 4x4 register tile.
__global__ __launch_bounds__(256, 4) void wo_kernel(
    const float* __restrict__ Zr, const float* __restrict__ Wo,
    float* __restrict__ Dp) {
  __shared__ float zs[64 * WS];      // [kk][row]
  __shared__ float wl[64 * WS];      // [kk][col]
  const int tid  = threadIdx.x;
  const int col0 = blockIdx.x * 64;
  const int ks   = blockIdx.y;
  const int kb   = ks * 64;
  const int tc = tid & 15, tr = tid >> 4;

  #pragma unroll
  for (int i = 0; i < 4; i++) {
    int e = i * 256 + tid;
    int r = e >> 4, q = e & 15;
    float4 v = *(const float4*)(Zr + r * 1024 + kb + q * 4);
    zs[(q * 4 + 0) * WS + r] = v.x;
    zs[(q * 4 + 1) * WS + r] = v.y;
    zs[(q * 4 + 2) * WS + r] = v.z;
    zs[(q * 4 + 3) * WS + r] = v.w;
    float4 w = *(const float4*)(Wo + (size_t)(kb + r) * 1024 + col0 + q * 4);
    *(float4*)(wl + r * WS + q * 4) = w;
  }
  __syncthreads();

  float acc[4][4];
  #pragma unroll
  for (int i = 0; i < 4; i++)
    #pragma unroll
    for (int j = 0; j < 4; j++) acc[i][j] = 0.f;

  #pragma unroll 8
  for (int kk = 0; kk < 64; kk++) {
    float4 xv = *(const float4*)(zs + kk * WS + tr * 4);
    float4 wv = *(const float4*)(wl + kk * WS + tc * 4);
    acc[0][0] = fmaf(xv.x, wv.x, acc[0][0]);
    acc[0][1] = fmaf(xv.x, wv.y, acc[0][1]);
    acc[0][2] = fmaf(xv.x, wv.z, acc[0][2]);
    acc[0][3] = fmaf(xv.x, wv.w, acc[0][3]);
    acc[1][0] = fmaf(xv.y, wv.x, acc[1][0]);
    acc[1][1] = fmaf(xv.y, wv.y, acc[1][1]);
    acc[1][2] = fmaf(xv.y, wv.z, acc[1][2]);
    acc[1][3] = fmaf(xv.y, wv.w, acc[1][3]);
    acc[2][0] = fmaf(xv.z, wv.x, acc[2][0]);
    acc[2][1] = fmaf(xv.z, wv.y, acc[2][1]);
    acc[2][2] = fmaf(xv.z, wv.z, acc[2][2]);
    acc[2][3] = fmaf(xv.z, wv.w, acc[2][3]);
    acc[3][0] = fmaf(xv.w, wv.x, acc[3][0]);
    acc[3][1] = fmaf(xv.w, wv.y, acc[3][1]);
    acc[3][2] = fmaf(xv.w, wv.z, acc[3][2]);
    acc[3][3] = fmaf(xv.w, wv.w, acc[3][3]);
  }

  float* __restrict__ D = Dp + ks * DP_STR + col0;
  #pragma unroll
  for (int i = 0; i < 4; i++) {
    float4 o = make_float4(acc[i][0], acc[i][1], acc[i][2], acc[i][3]);
    *(float4*)(D + (tr * 4 + i) * 1024 + tc * 4) = o;
  }
}

// ---- kernel D: window rows only: out = LN(x + sum of 16 delta partials) ---
__global__ __launch_bounds__(256, 4) void ln_win_kernel(
    const float4* __restrict__ x4, const float4* __restrict__ dp4,
    const float4* __restrict__ g4, const float4* __restrict__ b4,
    float4* __restrict__ out4) {
  const int tid = threadIdx.x;
  const int wave = tid >> 6, lane = tid & 63;
  const int wr  = blockIdx.x * 4 + wave;               // 0..63
  const int row = (wr >> 5) * 2048 + 2016 + (wr & 31);

  float4 v[4];
  #pragma unroll
  for (int i = 0; i < 4; i++) v[i] = x4[row * 256 + i * 64 + lane];
  #pragma unroll
  for (int p = 0; p < NKS_W; p++) {
    #pragma unroll
    for (int i = 0; i < 4; i++) {
      float4 d = dp4[p * 16384 + wr * 256 + i * 64 + lane];
      v[i].x += d.x; v[i].y += d.y; v[i].z += d.z; v[i].w += d.w;
    }
  }
  float sum = 0.f, ss = 0.f;
  #pragma unroll
  for (int i = 0; i < 4; i++) {
    sum += v[i].x + v[i].y + v[i].z + v[i].w;
    ss  += v[i].x * v[i].x + v[i].y * v[i].y + v[i].z * v[i].z + v[i].w * v[i].w;
  }
  #pragma unroll
  for (int off = 1; off < 64; off <<= 1) {
    sum += __shfl_xor(sum, off);
    ss  += __shfl_xor(ss, off);
  }
  float mu   = sum * (1.f / 1024.f);
  float rstd = rsqrtf(ss * (1.f / 1024.f) - mu * mu + 1e-5f);

  #pragma unroll
  for (int i = 0; i < 4; i++) {
    float4 g = g4[i * 64 + lane];
    float4 be = b4[i * 64 + lane];
    float4 o;
    o.x = (v[i].x - mu) * rstd * g.x + be.x;
    o.y = (v[i].y - mu) * rstd * g.y + be.y;
    o.z = (v[i].z - mu) * rstd * g.z + be.z;
    o.w = (v[i].w - mu) * rstd * g.w + be.w;
    out4[row * 256 + i * 64 + lane] = o;
  }
}

// ---------------------------------------------------------------------------
extern "C" void kernel_launch(void* const* d_in, const int* in_sizes, int n_in,
                              void* d_out, int out_size, void* d_ws, size_t ws_size,
                              hipStream_t stream) {
  const float* x   = (const float*)d_in[0];
  const float* Wq  = (const float*)d_in[1];
  const float* Wk  = (const float*)d_in[2];
  const float* Wv  = (const float*)d_in[3];  // NB: dict order, W_V before W_Kp
  const float* Wkp = (const float*)d_in[4];
  const float* Wo  = (const float*)d_in[5];
  const float* gam = (const float*)d_in[6];
  const float* bet = (const float*)d_in[7];
  float* out = (float*)d_out;
  float* ws  = (float*)d_ws;   // needs 12.9 MB (harness provides ~256 MB)

  hipLaunchKernelGGL(proj_ln_kernel, dim3(512 + 448), dim3(256), 0, stream,
                     x, Wq, Wk, Wkp, Wv, gam, bet, ws, out);
  hipLaunchKernelGGL(attn_kernel, dim3(8, 16, 2), dim3(256), 0, stream,
                     ws, ws + ZF_OFF);
  hipLaunchKernelGGL(wo_kernel, dim3(16, NKS_W), dim3(256), 0, stream,
                     ws + ZF_OFF, Wo, ws + DP_OFF);
  hipLaunchKernelGGL(ln_win_kernel, dim3(16), dim3(256), 0, stream,
                     (const float4*)x, (const float4*)(ws + DP_OFF),
                     (const float4*)gam, (const float4*)bet, (float4*)out);
}